// Round 18
// baseline (296.922 us; speedup 1.0000x reference)
//
#include <hip/hip_runtime.h>
#include <hip/hip_bf16.h>
#include <stdint.h>

#define B_SZ 8192
#define D_SZ 1024
#define H_SZ 1024
#define O_SZ 512
#define E_SZ 8

typedef float f32x4 __attribute__((ext_vector_type(4)));
typedef __bf16 bf16x8 __attribute__((ext_vector_type(8)));

typedef __attribute__((address_space(1))) uint32_t gu32;
typedef __attribute__((address_space(3))) uint32_t lu32;

__device__ __forceinline__ unsigned short f2bf(float f) {
    union { __hip_bfloat16 h; unsigned short u; } c;
    c.h = __float2bfloat16(f);
    return c.u;
}
__device__ __forceinline__ float bf2f(unsigned short u) {
    union { float f; uint32_t u; } c;
    c.u = ((uint32_t)u) << 16;
    return c.f;
}

// ---------------- fused prep: convert | W1 transpose | W2 transpose | gates ----------------
__global__ __launch_bounds__(512) void k_prep(const float* __restrict__ x,
                                              const float* __restrict__ W1,
                                              const float* __restrict__ W2,
                                              const float* __restrict__ Wg,
                                              const float* __restrict__ Wgs,
                                              unsigned short* __restrict__ x_bf,
                                              unsigned short* __restrict__ W1T,
                                              unsigned short* __restrict__ W2T,
                                              float* __restrict__ g_all) {
    __shared__ __align__(16) char smem[72192];
    const int blk = blockIdx.x;
    const int tid = threadIdx.x;

    if (blk < 2048) {
        const int i = blk * 512 + tid;
        const float4* p = (const float4*)x + (size_t)i * 2;
        float4 a = p[0], b = p[1];
        ushort4 lo, hi;
        lo.x = f2bf(a.x); lo.y = f2bf(a.y); lo.z = f2bf(a.z); lo.w = f2bf(a.w);
        hi.x = f2bf(b.x); hi.y = f2bf(b.y); hi.z = f2bf(b.z); hi.w = f2bf(b.w);
        ushort4* q = (ushort4*)x_bf + (size_t)i * 2;
        q[0] = lo; q[1] = hi;
        return;
    }

    if (blk < 5120) {
        const float* in; unsigned short* outp; int R, C, e, rem;
        if (blk < 4096) {
            const int local = blk - 2048;
            in = W1; outp = W1T; R = D_SZ; C = H_SZ;
            e = local >> 8; rem = local & 255;
        } else {
            const int local = blk - 4096;
            in = W2; outp = W2T; R = H_SZ; C = O_SZ;
            e = local >> 7; rem = local & 127;
        }
        const int ncx = C >> 6;
        const int c0 = (rem % ncx) * 64, r0 = (rem / ncx) * 64;
        float (*tile)[65] = (float(*)[65])smem;
        const float* src = in + (size_t)e * R * C;
        unsigned short* dst = outp + (size_t)e * R * C;
        const int tx = tid & 63, ty = tid >> 6;
#pragma unroll
        for (int rr = ty; rr < 64; rr += 8)
            tile[rr][tx] = src[(size_t)(r0 + rr) * C + c0 + tx];
        __syncthreads();
#pragma unroll
        for (int rr = ty; rr < 64; rr += 8)
            dst[(size_t)(c0 + rr) * R + r0 + tx] = f2bf(tile[tx][rr]);
        return;
    }

    {
        const int bl = blk - 5120;
        unsigned short* wlds = (unsigned short*)smem;
        float (*logits)[24] = (float(*)[24])(smem + 66048);

        for (int idx = tid; idx < 32 * 1024; idx += 512) {
            const int j = idx >> 10, k = idx & 1023;
            float v = 0.f;
            if (j < 6)       v = Wg[(size_t)k * 6 + j];
            else if (j < 12) v = Wg[(size_t)D_SZ * 6 + (size_t)k * 6 + (j - 6)];
            else if (j < 20) v = Wgs[(size_t)k * 8 + (j - 12)];
            wlds[j * 1032 + k] = f2bf(v);
        }
        __syncthreads();

        const int lane = tid & 63, w = tid >> 6;
        const int rt = w >> 1, jt = w & 1;
        const int lr = lane & 15, lg = lane >> 4;
        const int row0 = bl * 64 + rt * 16;

        const float* xr = x + (size_t)(row0 + lr) * D_SZ;
        const unsigned short* wrow = &wlds[(jt * 16 + lr) * 1032];

        f32x4 acc = f32x4{0.f, 0.f, 0.f, 0.f};
#pragma unroll 4
        for (int kt = 0; kt < 32; ++kt) {
            float4 a0 = *(const float4*)(xr + kt * 32 + lg * 8);
            float4 a1 = *(const float4*)(xr + kt * 32 + lg * 8 + 4);
            union { unsigned short us[8]; bf16x8 v; } fa;
            fa.us[0] = f2bf(a0.x); fa.us[1] = f2bf(a0.y);
            fa.us[2] = f2bf(a0.z); fa.us[3] = f2bf(a0.w);
            fa.us[4] = f2bf(a1.x); fa.us[5] = f2bf(a1.y);
            fa.us[6] = f2bf(a1.z); fa.us[7] = f2bf(a1.w);
            bf16x8 fb = *(const bf16x8*)(wrow + kt * 32 + lg * 8);
            acc = __builtin_amdgcn_mfma_f32_16x16x32_bf16(fa.v, fb, acc, 0, 0, 0);
        }
        const int j = jt * 16 + lr;
        if (j < 24) {
#pragma unroll
            for (int r = 0; r < 4; ++r)
                logits[rt * 16 + lg * 4 + r][j] = acc[r];
        }
        __syncthreads();

        if (tid < 64) {
            const int row = tid;
            float* g = g_all + (size_t)(bl * 64 + row) * 20;
#pragma unroll
            for (int t = 0; t < 3; ++t) {
                const int base = (t == 0) ? 0 : (t == 1 ? 6 : 12);
                const int cnt  = (t == 2) ? 8 : 6;
                float m = -1e30f;
                for (int q = 0; q < cnt; ++q) m = fmaxf(m, logits[row][base + q]);
                float ex[8]; float sum = 0.f;
                for (int q = 0; q < cnt; ++q) { ex[q] = __expf(logits[row][base + q] - m); sum += ex[q]; }
                float inv = 1.f / sum;
                for (int q = 0; q < cnt; ++q) g[base + q] = ex[q] * inv;
            }
        }
    }
}

// ------- 256x256 bf16 GEMM: ring-4 BK=32, one-phase-ahead reads, DEPTH-8 counted vmcnt -------
// VERIFIED round-16 schedule (G1 = 140.3 us, 42.6% MfmaUtil, passed). The r17
// barrier-merge raced (reads of t+1 preceded the only wait that guaranteed it landed);
// this 4-barrier split is load-bearing: at each U-phase wait point 12 loads are
// outstanding so vmcnt(8) provably drains all of t+1 (m135 oldest-first).
__global__ __launch_bounds__(512, 2) void k_gemm_pipe(
    const unsigned short* __restrict__ A,
    const unsigned short* __restrict__ Bt,
    const float* __restrict__ bias,
    unsigned short* __restrict__ C,
    int M, int N, int K,
    long long sA, long long sB, long long sBias, long long sC, int e_base) {

    const int tid = threadIdx.x;
    const int lane = tid & 63, wid = tid >> 6;
    const int wr = wid >> 2, wc = wid & 3;       // 2 x 4 wave grid
    const int lr = lane & 15, lg = lane >> 4;

    const int nwg = gridDim.x;
    const int wg = blockIdx.x;
    const int swz = (wg & 7) * (nwg >> 3) + (wg >> 3);
    const int nx = N >> 8;
    const int my = M >> 8;
    const int bx = swz % nx;
    const int t1 = swz / nx;
    const int by = t1 % my;
    const int e  = t1 / my + e_base;

    A    += (size_t)((long long)e * sA);
    Bt   += (size_t)((long long)e * sB);
    bias += (size_t)((long long)e * sBias);
    C    += (size_t)((long long)e * sC);

    const int m0 = by * 256, n0 = bx * 256;

    __shared__ __align__(16) unsigned short lds[65536];   // 128 KiB
    char* ldsb = (char*)lds;

    const int srow = tid >> 2;
    const int scol = (((tid & 3) ^ ((tid >> 3) & 3)) * 8);
    const int sdst = tid * 16;

    auto stageA2 = [&](int t) {
        const int bb = (t & 3) * 32768;
        const unsigned short* s0 = A + (size_t)(m0 + srow) * K + (t << 5) + scol;
        __builtin_amdgcn_global_load_lds((gu32*)s0, (lu32*)(ldsb + bb + sdst), 16, 0, 0);
        __builtin_amdgcn_global_load_lds((gu32*)(s0 + (size_t)128 * K),
                                         (lu32*)(ldsb + bb + 8192 + sdst), 16, 0, 0);
    };
    auto stageB2 = [&](int t) {
        const int bb = (t & 3) * 32768 + 16384;
        const unsigned short* s0 = Bt + (size_t)(n0 + srow) * K + (t << 5) + scol;
        __builtin_amdgcn_global_load_lds((gu32*)s0, (lu32*)(ldsb + bb + sdst), 16, 0, 0);
        __builtin_amdgcn_global_load_lds((gu32*)(s0 + (size_t)128 * K),
                                         (lu32*)(ldsb + bb + 8192 + sdst), 16, 0, 0);
    };

    const int cblk = (lg ^ ((lr >> 1) & 3)) * 16;
    const int aoff = wr * 8192 + lr * 64 + cblk;
    const int boff = 16384 + (wc >> 1) * 8192 + (wc & 1) * 4096 + lr * 64 + cblk;

    f32x4 acc[8][4];
#pragma unroll
    for (int i = 0; i < 8; ++i)
#pragma unroll
        for (int j = 0; j < 4; ++j)
            acc[i][j] = f32x4{0.f, 0.f, 0.f, 0.f};

    auto mfma16 = [&](const bf16x8 (&fa)[4], const bf16x8 (&fb)[4], int rbase) {
        __builtin_amdgcn_s_setprio(1);
#pragma unroll
        for (int i = 0; i < 4; ++i)
#pragma unroll
            for (int j = 0; j < 4; ++j)
                acc[rbase + i][j] = __builtin_amdgcn_mfma_f32_16x16x32_bf16(
                    fa[i], fb[j], acc[rbase + i][j], 0, 0, 0);
        __builtin_amdgcn_s_setprio(0);
    };

    const int NT = K >> 5;   // 32 (divisible by 4)

    // prologue: stage tiles 0,1,2 (12 glds); vmcnt(8) -> tile 0 landed
    stageA2(0); stageB2(0); stageA2(1); stageB2(1); stageA2(2); stageB2(2);
    asm volatile("s_waitcnt vmcnt(8)" ::: "memory");
    asm volatile("s_barrier" ::: "memory");

    bf16x8 aU0[4], aL0[4], b0[4], aU1[4], aL1[4], b1v[4];
#pragma unroll
    for (int i = 0; i < 4; ++i) aU0[i] = *(const bf16x8*)(ldsb + aoff + i * 1024);
#pragma unroll
    for (int j = 0; j < 4; ++j) b0[j]  = *(const bf16x8*)(ldsb + boff + j * 1024);

#pragma unroll 2
    for (int t = 0; t < NT; t += 2) {
        const int bb0 = (t & 3) * 32768;
        const int bb1 = ((t + 1) & 3) * 32768;
        const int bb2 = ((t + 2) & 3) * 32768;

        // ---- phase (t,U): read L-frags(t); stage A+B(t+3); depth-8 wait; MFMA U(t) ----
#pragma unroll
        for (int i = 0; i < 4; ++i) aL0[i] = *(const bf16x8*)(ldsb + bb0 + aoff + (4 + i) * 1024);
        if (t + 3 < NT) { stageA2(t + 3); stageB2(t + 3);
                          asm volatile("s_waitcnt vmcnt(8)" ::: "memory"); }
        else if (t + 2 < NT) { asm volatile("s_waitcnt vmcnt(4)" ::: "memory"); }
        else                 { asm volatile("s_waitcnt vmcnt(0)" ::: "memory"); }
        asm volatile("s_barrier" ::: "memory");
        mfma16(aU0, b0, 0);

        // ---- phase (t,L): read U-frags(t+1); MFMA L(t) ----
#pragma unroll
        for (int i = 0; i < 4; ++i) aU1[i] = *(const bf16x8*)(ldsb + bb1 + aoff + i * 1024);
#pragma unroll
        for (int j = 0; j < 4; ++j) b1v[j] = *(const bf16x8*)(ldsb + bb1 + boff + j * 1024);
        asm volatile("s_barrier" ::: "memory");
        mfma16(aL0, b0, 4);

        // ---- phase (t+1,U): read L-frags(t+1); stage A+B(t+4); depth-8 wait; MFMA U(t+1) ----
#pragma unroll
        for (int i = 0; i < 4; ++i) aL1[i] = *(const bf16x8*)(ldsb + bb1 + aoff + (4 + i) * 1024);
        if (t + 4 < NT) { stageA2(t + 4); stageB2(t + 4);
                          asm volatile("s_waitcnt vmcnt(8)" ::: "memory"); }
        else if (t + 3 < NT) { asm volatile("s_waitcnt vmcnt(4)" ::: "memory"); }
        else                 { asm volatile("s_waitcnt vmcnt(0)" ::: "memory"); }
        asm volatile("s_barrier" ::: "memory");
        mfma16(aU1, b1v, 0);

        // ---- phase (t+1,L): read U-frags(t+2); MFMA L(t+1) ----
        if (t + 2 < NT) {
#pragma unroll
            for (int i = 0; i < 4; ++i) aU0[i] = *(const bf16x8*)(ldsb + bb2 + aoff + i * 1024);
#pragma unroll
            for (int j = 0; j < 4; ++j) b0[j]  = *(const bf16x8*)(ldsb + bb2 + boff + j * 1024);
        }
        asm volatile("s_barrier" ::: "memory");
        mfma16(aL1, b1v, 4);
    }

    // ---- epilogue: bias + relu -> LDS tile -> coalesced dwordx4 stores ----
    __syncthreads();
    unsigned short* ct = (unsigned short*)ldsb;
#pragma unroll
    for (int j = 0; j < 4; ++j) {
        const int nn = wc * 64 + j * 16 + lr;
        const float bv = bias[n0 + nn];
#pragma unroll
        for (int i = 0; i < 8; ++i) {
            const int mb = wr * 128 + i * 16 + lg * 4;
#pragma unroll
            for (int r = 0; r < 4; ++r) {
                float v = fmaxf(acc[i][j][r] + bv, 0.f);
                ct[(size_t)(mb + r) * 256 + nn] = f2bf(v);
            }
        }
    }
    __syncthreads();
#pragma unroll
    for (int it = 0; it < 16; ++it) {
        const int row = it * 16 + (tid >> 5);
        const int colE = (tid & 31) * 8;
        *(int4*)(&C[(size_t)(m0 + row) * N + n0 + colE]) =
            *(const int4*)(ldsb + it * 8192 + (size_t)tid * 16);
    }
}

// ---------------- combine: out[b][t][o], 8 o's per thread ----------------
__global__ __launch_bounds__(256) void k_combine(const unsigned short* __restrict__ eo,
                                                 const float* __restrict__ g_all,
                                                 float* __restrict__ out) {
    int idx8 = blockIdx.x * 256 + threadIdx.x;    // over B*O/8
    int b = idx8 >> 6;                            // O/8 = 64
    int o8 = (idx8 & 63) * 8;
    const float* g = g_all + (size_t)b * 20;
    float v[E_SZ][8];
#pragma unroll
    for (int e = 0; e < E_SZ; ++e) {
        const unsigned short* p = eo + (size_t)e * B_SZ * O_SZ + (size_t)b * O_SZ + o8;
        int4 u = *(const int4*)p;
        const unsigned short* us = (const unsigned short*)&u;
#pragma unroll
        for (int c = 0; c < 8; ++c) v[e][c] = bf2f(us[c]);
    }
    float r0[8], r1[8], r2[8];
#pragma unroll
    for (int c = 0; c < 8; ++c) {
        r0[c] = g[0] * v[0][c] + g[1] * v[1][c] + g[2] * v[4][c] + g[3] * v[5][c]
              + g[4] * v[6][c] + g[5] * v[7][c];
        r1[c] = g[6] * v[2][c] + g[7] * v[3][c] + g[8] * v[4][c] + g[9] * v[5][c]
              + g[10] * v[6][c] + g[11] * v[7][c];
        float s = 0.f;
#pragma unroll
        for (int e = 0; e < E_SZ; ++e) s += g[12 + e] * v[e][c];
        r2[c] = s;
    }
    size_t ob = (size_t)b * (3 * O_SZ) + o8;
    *(float4*)(out + ob)             = *(float4*)&r0[0];
    *(float4*)(out + ob + 4)         = *(float4*)&r0[4];
    *(float4*)(out + ob + O_SZ)      = *(float4*)&r1[0];
    *(float4*)(out + ob + O_SZ + 4)  = *(float4*)&r1[4];
    *(float4*)(out + ob + 2 * O_SZ)  = *(float4*)&r2[0];
    *(float4*)(out + ob + 2 * O_SZ + 4) = *(float4*)&r2[4];
}

extern "C" void kernel_launch(void* const* d_in, const int* in_sizes, int n_in,
                              void* d_out, int out_size, void* d_ws, size_t ws_size,
                              hipStream_t stream) {
    const float* x   = (const float*)d_in[0];
    const float* W1  = (const float*)d_in[1];
    const float* b1  = (const float*)d_in[2];
    const float* W2  = (const float*)d_in[3];
    const float* b2  = (const float*)d_in[4];
    const float* Wg  = (const float*)d_in[5];
    const float* Wgs = (const float*)d_in[6];
    float* out = (float*)d_out;

    char* ws = (char*)d_ws;
    const size_t SZ_XBF  = (size_t)B_SZ * D_SZ * 2;           // 16 MB
    const size_t SZ_W1T  = (size_t)E_SZ * H_SZ * D_SZ * 2;    // 16 MB
    const size_t SZ_W2T  = (size_t)E_SZ * O_SZ * H_SZ * 2;    // 8 MB
    const size_t SZ_EO   = (size_t)E_SZ * B_SZ * O_SZ * 2;    // 64 MB
    const size_t SZ_G    = (size_t)B_SZ * 20 * 4;             // 640 KB
    const size_t SZ_HBIG = (size_t)E_SZ * B_SZ * H_SZ * 2;    // 128 MB

    unsigned short* x_bf = (unsigned short*)ws;              ws += SZ_XBF;
    unsigned short* W1T  = (unsigned short*)ws;              ws += SZ_W1T;
    unsigned short* W2T  = (unsigned short*)ws;              ws += SZ_W2T;
    unsigned short* eo   = (unsigned short*)ws;              ws += SZ_EO;
    float* g_all         = (float*)ws;                       ws += SZ_G;
    unsigned short* h_buf = (unsigned short*)ws;

    const size_t fixed = SZ_XBF + SZ_W1T + SZ_W2T + SZ_EO + SZ_G;
    const bool big = ws_size >= fixed + SZ_HBIG;

    // 1) fused prep: convert | transposes | gates  (one launch)
    k_prep<<<5248, 512, 0, stream>>>(x, W1, W2, Wg, Wgs, x_bf, W1T, W2T, g_all);

    // 2) expert GEMMs (256x256 tiles; flat 1D grids, all % 8 == 0)
    if (big) {
        k_gemm_pipe<<<(H_SZ / 256) * (B_SZ / 256) * E_SZ, 512, 0, stream>>>(
            x_bf, W1T, b1, h_buf, B_SZ, H_SZ, D_SZ,
            0LL, (long long)H_SZ * D_SZ, (long long)H_SZ, (long long)B_SZ * H_SZ, 0);
        k_gemm_pipe<<<(O_SZ / 256) * (B_SZ / 256) * E_SZ, 512, 0, stream>>>(
            h_buf, W2T, b2, eo, B_SZ, O_SZ, H_SZ,
            (long long)B_SZ * H_SZ, (long long)O_SZ * H_SZ, (long long)O_SZ, (long long)B_SZ * O_SZ, 0);
    } else {
        for (int e = 0; e < E_SZ; ++e) {
            k_gemm_pipe<<<(H_SZ / 256) * (B_SZ / 256), 512, 0, stream>>>(
                x_bf, W1T, b1, h_buf, B_SZ, H_SZ, D_SZ,
                0LL, (long long)H_SZ * D_SZ, (long long)H_SZ, 0LL, e);
            k_gemm_pipe<<<(O_SZ / 256) * (B_SZ / 256), 512, 0, stream>>>(
                h_buf, W2T, b2, eo, B_SZ, O_SZ, H_SZ,
                0LL, (long long)O_SZ * H_SZ, (long long)O_SZ, (long long)B_SZ * O_SZ, e);
        }
    }

    // 3) combine
    k_combine<<<(B_SZ * O_SZ / 8) / 256, 256, 0, stream>>>(eo, g_all, out);
}